// Round 10
// baseline (289.863 us; speedup 1.0000x reference)
//
#include <hip/hip_runtime.h>
#include <hip/hip_bf16.h>
#include <cstddef>

// K=2048, B=4, D=5, ATOM=125, BOND=12, HID=125, OUT=40
// NOFF = [0, 2048, 10240, 43008, 175104, 699392]
// BOFF = [0, 8192, 40960, 172032, 696320]
//
// Round 10 = round 9 + leaf/d3 fusion (perfect 128-row block locality):
//   fused_ld3 (4096 blocks): pass1 leaf rows [128b,128b+128) -> lout LDS;
//   pass2 d3 edges [128b,..) reading child frags straight from lout ->
//   sibling-summed parents [32b,32b+32) to global f16. Saves the 42 MB
//   leaf-output HBM round trip (84 MB traffic) + one launch.
// d2/d1/d0 + prep kernels: round-9 verbatim (validated).
// Pipeline per pass (r9-validated): double-buffered LDS X/W; per chunk
//   [issue c_{j+2}->regs] [MFMA c_j] [ds_write c_{j+1}] [lgkmcnt(0); s_barrier]
// (barrier never drains vmcnt; counted vmcnt lands at the ds_write).
// f16 everywhere, RNE packing. k' layout (192): [0,125) msg, [125,128) 0,
// [128,140) bond, [140,144) 0, [144,184) child, [184,192) 0.

typedef __attribute__((ext_vector_type(8))) _Float16 h8;
typedef __attribute__((ext_vector_type(4))) float f32x4;
typedef __attribute__((ext_vector_type(4))) unsigned int v4u;

static constexpr int HID = 125, OUT = 40;
static constexpr int XS = 40;  // LDS row stride (f16): 80B, 16B-aligned

__device__ __forceinline__ unsigned short f2h(float x) {
    _Float16 h = (_Float16)x;  // RNE
    return __builtin_bit_cast(unsigned short, h);
}
__device__ __forceinline__ unsigned int pkh(float a, float b) {
    return (unsigned int)f2h(a) | ((unsigned int)f2h(b) << 16);
}

__global__ void prep_w1(const float* __restrict__ W1, unsigned short* __restrict__ w1f) {
    int idx = blockIdx.x * 256 + threadIdx.x;
    if (idx >= 128 * 192) return;
    int hid = idx / 192, kp = idx % 192;
    int k = (kp < 125) ? kp
          : (kp >= 128 && kp < 140) ? kp - 3
          : (kp >= 144 && kp < 184) ? kp - 7 : -1;
    float v = (k >= 0 && hid < HID) ? W1[(size_t)k * HID + hid] : 0.f;
    w1f[idx] = f2h(v);
}

// W2 frag-packed (layer2 B), validated mapping.
__global__ void prep_w2(const float* __restrict__ W2, unsigned int* __restrict__ w2f) {
    int t = threadIdx.x;
    for (int task = t; task < 12 * 64; task += 256) {
        int ln = task & 63, fr = task >> 6;
        int kt = fr / 3, qt = fr % 3;
        int q = qt * 16 + (ln & 15);
        unsigned int w[4];
#pragma unroll
        for (int jp = 0; jp < 4; jp++) {
            unsigned short e[2];
#pragma unroll
            for (int s = 0; s < 2; s++) {
                int j = jp * 2 + s;
                int hid = kt * 32 + ((j >> 2) << 4) + ((ln >> 4) << 2) + (j & 3);
                float v = (hid < HID && q < OUT) ? W2[(size_t)hid * OUT + q] : 0.f;
                e[s] = f2h(v);
            }
            w[jp] = (unsigned int)e[0] | ((unsigned int)e[1] << 16);
        }
        v4u val = {w[0], w[1], w[2], w[3]};
        ((v4u*)w2f)[fr * 64 + ln] = val;
    }
}

// ===================== round-9 level kernel (verbatim) =====================
// MODE 1: mid (msg by row>>2, bond+child, sibling-summed f16 out).
// MODE 2: final (like 1, fp32 out).
template <int NC, int MODE>
__global__ void __launch_bounds__(256, 3)
level_k(const float* __restrict__ msg, const float* __restrict__ bonds,
        const unsigned short* __restrict__ child,
        const unsigned short* __restrict__ w1f, const unsigned int* __restrict__ w2f,
        const float* __restrict__ b1, const float* __restrict__ b2,
        void* __restrict__ outp) {
    __shared__ __align__(16) unsigned short Xb[2][128 * XS];
    __shared__ __align__(16) unsigned short Wb[2][128 * XS];

    const int tid = threadIdx.x;
    const int lane = tid & 63;
    const int wv = tid >> 6;
    const int l15 = tid & 15;
    const int l16 = (tid >> 4) & 3;
    const int c4 = tid & 3;
    const int rw = tid >> 2;
    const int wr_ = tid >> 1;
    const int whf = tid & 1;
    const int base = blockIdx.x * 128;

    float fst[2][2][8];
    v4u cst[2][2];
    v4u wst[2][2];

    auto issue = [&](int j, int s) {
        const unsigned short* gw = w1f + (size_t)wr_ * 192 + j * 32 + whf * 16;
        wst[s][0] = *(const v4u*)gw;
        wst[s][1] = *(const v4u*)(gw + 8);
#pragma unroll
        for (int p = 0; p < 2; p++) {
            int row = base + rw + 64 * p;
            if (j <= 3) {
                int mr = (row >> 2);
                const float* mp = msg + (size_t)mr * 125;
#pragma unroll
                for (int i = 0; i < 8; i++) {
                    int k = j * 32 + c4 * 8 + i;
                    fst[s][p][i] = (k < 125) ? mp[k] : 0.f;
                }
            } else if (j == 4) {
                if (c4 < 2) {
                    const float* bp = bonds + (size_t)row * 12;
#pragma unroll
                    for (int i = 0; i < 8; i++) {
                        int c = c4 * 8 + i;
                        fst[s][p][i] = (c < 12) ? bp[c] : 0.f;
                    }
                } else {
                    cst[s][p] = *(const v4u*)&child[(size_t)row * 40 + (c4 - 2) * 8];
                }
            } else {
                if (c4 < 3) {
                    cst[s][p] = *(const v4u*)&child[(size_t)row * 40 + 16 + c4 * 8];
                } else {
                    v4u z = {0, 0, 0, 0};
                    cst[s][p] = z;
                }
            }
        }
    };

    auto stage = [&](int j, int s, int buf) {
        *(v4u*)&Wb[buf][wr_ * XS + whf * 16] = wst[s][0];
        *(v4u*)&Wb[buf][wr_ * XS + whf * 16 + 8] = wst[s][1];
#pragma unroll
        for (int p = 0; p < 2; p++) {
            int row = rw + 64 * p;
            unsigned short* slot = &Xb[buf][row * XS + c4 * 8];
            if (j <= 3 || (j == 4 && c4 < 2)) {
                v4u val = {pkh(fst[s][p][0], fst[s][p][1]), pkh(fst[s][p][2], fst[s][p][3]),
                           pkh(fst[s][p][4], fst[s][p][5]), pkh(fst[s][p][6], fst[s][p][7])};
                *(v4u*)slot = val;
            } else {
                *(v4u*)slot = cst[s][p];
            }
        }
    };

    f32x4 acc[8][2];
#pragma unroll
    for (int mt = 0; mt < 8; mt++) {
        f32x4 bi;
#pragma unroll
        for (int r = 0; r < 4; r++) {
            int h_ = mt * 16 + l16 * 4 + r;
            bi[r] = (h_ < HID) ? b1[h_] : 0.f;
        }
        acc[mt][0] = bi;
        acc[mt][1] = bi;
    }

    issue(0, 0);
    issue(1, 1);
    stage(0, 0, 0);
    asm volatile("s_waitcnt lgkmcnt(0)\n\ts_barrier" ::: "memory");

#pragma unroll
    for (int j = 0; j < NC; ++j) {
        if (j + 2 < NC) issue(j + 2, j & 1);
        {
            h8 xf0 = *(const h8*)&Xb[j & 1][(wv * 32 + l15) * XS + l16 * 8];
            h8 xf1 = *(const h8*)&Xb[j & 1][(wv * 32 + 16 + l15) * XS + l16 * 8];
#pragma unroll
            for (int mt = 0; mt < 8; ++mt) {
                h8 wf = *(const h8*)&Wb[j & 1][(mt * 16 + l15) * XS + l16 * 8];
                acc[mt][0] = __builtin_amdgcn_mfma_f32_16x16x32_f16(wf, xf0, acc[mt][0], 0, 0, 0);
                acc[mt][1] = __builtin_amdgcn_mfma_f32_16x16x32_f16(wf, xf1, acc[mt][1], 0, 0, 0);
            }
        }
        if (j + 1 < NC) {
            stage(j + 1, (j + 1) & 1, (j + 1) & 1);
            asm volatile("s_waitcnt lgkmcnt(0)\n\ts_barrier" ::: "memory");
        }
    }

#pragma unroll
    for (int mt = 0; mt < 8; mt++)
#pragma unroll
        for (int nt = 0; nt < 2; nt++)
#pragma unroll
            for (int r = 0; r < 4; r++)
                acc[mt][nt][r] = fmaxf(acc[mt][nt][r], 0.01f * acc[mt][nt][r]);

    float b2v[3];
#pragma unroll
    for (int qt = 0; qt < 3; qt++) {
        int q = qt * 16 + l15;
        b2v[qt] = (q < OUT) ? b2[q] : 0.f;
    }
#pragma unroll
    for (int nt = 0; nt < 2; ++nt) {
        h8 A[4];
#pragma unroll
        for (int kt = 0; kt < 4; kt++) {
            v4u av = {pkh(acc[2 * kt][nt][0], acc[2 * kt][nt][1]),
                      pkh(acc[2 * kt][nt][2], acc[2 * kt][nt][3]),
                      pkh(acc[2 * kt + 1][nt][0], acc[2 * kt + 1][nt][1]),
                      pkh(acc[2 * kt + 1][nt][2], acc[2 * kt + 1][nt][3])};
            A[kt] = __builtin_bit_cast(h8, av);
        }
        const int tb = wv * 32 + nt * 16;
#pragma unroll
        for (int qt = 0; qt < 3; ++qt) {
            f32x4 o = {0.f, 0.f, 0.f, 0.f};
#pragma unroll
            for (int kt = 0; kt < 4; kt++) {
                v4u wvv = ((const v4u*)w2f)[(kt * 3 + qt) * 64 + lane];
                o = __builtin_amdgcn_mfma_f32_16x16x32_f16(
                    A[kt], __builtin_bit_cast(h8, wvv), o, 0, 0, 0);
            }
            int q = qt * 16 + l15;
            float s = 0.f;
#pragma unroll
            for (int r = 0; r < 4; r++) {
                float v = o[r] + b2v[qt];
                s += fmaxf(v, 0.01f * v);
            }
            if (q < OUT) {
                int p = (base >> 2) + (tb >> 2) + l16;
                if (MODE == 1)
                    ((unsigned short*)outp)[(size_t)p * 40 + q] = f2h(s);
                else
                    ((float*)outp)[(size_t)p * 40 + q] = s;
            }
        }
    }
}

// ===================== fused leaf + d3 kernel =====================
__global__ void __launch_bounds__(256, 3)
fused_ld3(const float* __restrict__ msgL,   // leaf slice, row-indexed
          const float* __restrict__ msgM,   // d3 parent slice
          const float* __restrict__ bonds,  // d3 bond slice
          const unsigned short* __restrict__ w1f, const unsigned int* __restrict__ w2f,
          const float* __restrict__ b1, const float* __restrict__ b2,
          unsigned short* __restrict__ outp) {  // d3 parents, f16 [p][40]
    __shared__ __align__(16) unsigned short Xb[2][128 * XS];
    __shared__ __align__(16) unsigned short Wb[2][128 * XS];
    __shared__ __align__(16) unsigned short lout[128 * XS];  // leaf outputs

    const int tid = threadIdx.x;
    const int lane = tid & 63;
    const int wv = tid >> 6;
    const int l15 = tid & 15;
    const int l16 = (tid >> 4) & 3;
    const int c4 = tid & 3;
    const int rw = tid >> 2;
    const int wr_ = tid >> 1;
    const int whf = tid & 1;
    const int base = blockIdx.x * 128;

    float fst[2][2][8];
    v4u wst[2][2];

    auto issueW = [&](int j, int s) {
        const unsigned short* gw = w1f + (size_t)wr_ * 192 + j * 32 + whf * 16;
        wst[s][0] = *(const v4u*)gw;
        wst[s][1] = *(const v4u*)(gw + 8);
    };
    // pass 1 (leaf): msg by row, chunks 0..3 only
    auto issueX1 = [&](int j, int s) {
#pragma unroll
        for (int p = 0; p < 2; p++) {
            int row = base + rw + 64 * p;
            const float* mp = msgL + (size_t)row * 125;
#pragma unroll
            for (int i = 0; i < 8; i++) {
                int k = j * 32 + c4 * 8 + i;
                fst[s][p][i] = (k < 125) ? mp[k] : 0.f;
            }
        }
    };
    // pass 2 (d3): msg by row>>2 (chunks 0..3), bond (chunk 4, c4<2); child from lout
    auto issueX2 = [&](int j, int s) {
#pragma unroll
        for (int p = 0; p < 2; p++) {
            int row = base + rw + 64 * p;
            if (j <= 3) {
                const float* mp = msgM + (size_t)(row >> 2) * 125;
#pragma unroll
                for (int i = 0; i < 8; i++) {
                    int k = j * 32 + c4 * 8 + i;
                    fst[s][p][i] = (k < 125) ? mp[k] : 0.f;
                }
            } else if (j == 4 && c4 < 2) {
                const float* bp = bonds + (size_t)row * 12;
#pragma unroll
                for (int i = 0; i < 8; i++) {
                    int c = c4 * 8 + i;
                    fst[s][p][i] = (c < 12) ? bp[c] : 0.f;
                }
            }
        }
    };
    auto stageW = [&](int s, int buf) {
        *(v4u*)&Wb[buf][wr_ * XS + whf * 16] = wst[s][0];
        *(v4u*)&Wb[buf][wr_ * XS + whf * 16 + 8] = wst[s][1];
    };
    auto stageX = [&](int j, int s, int buf) {  // j<=3 always; j==4 only c4<2; j==5 none
        if (j >= 5 || (j == 4 && c4 >= 2)) return;
#pragma unroll
        for (int p = 0; p < 2; p++) {
            int row = rw + 64 * p;
            v4u val = {pkh(fst[s][p][0], fst[s][p][1]), pkh(fst[s][p][2], fst[s][p][3]),
                       pkh(fst[s][p][4], fst[s][p][5]), pkh(fst[s][p][6], fst[s][p][7])};
            *(v4u*)&Xb[buf][row * XS + c4 * 8] = val;
        }
    };

    float b2v[3];
#pragma unroll
    for (int qt = 0; qt < 3; qt++) {
        int q = qt * 16 + l15;
        b2v[qt] = (q < OUT) ? b2[q] : 0.f;
    }
    f32x4 bi0[8];
#pragma unroll
    for (int mt = 0; mt < 8; mt++) {
#pragma unroll
        for (int r = 0; r < 4; r++) {
            int h_ = mt * 16 + l16 * 4 + r;
            bi0[mt][r] = (h_ < HID) ? b1[h_] : 0.f;
        }
    }

    f32x4 acc[8][2];

    // =============== PASS 1: leaf (NC=4) ===============
#pragma unroll
    for (int mt = 0; mt < 8; mt++) { acc[mt][0] = bi0[mt]; acc[mt][1] = bi0[mt]; }

    issueX1(0, 0); issueW(0, 0);
    issueX1(1, 1); issueW(1, 1);
    stageX(0, 0, 0); stageW(0, 0);
    asm volatile("s_waitcnt lgkmcnt(0)\n\ts_barrier" ::: "memory");

#pragma unroll
    for (int j = 0; j < 4; ++j) {
        if (j + 2 < 4) { issueX1(j + 2, j & 1); issueW(j + 2, j & 1); }
        {
            h8 xf0 = *(const h8*)&Xb[j & 1][(wv * 32 + l15) * XS + l16 * 8];
            h8 xf1 = *(const h8*)&Xb[j & 1][(wv * 32 + 16 + l15) * XS + l16 * 8];
#pragma unroll
            for (int mt = 0; mt < 8; ++mt) {
                h8 wf = *(const h8*)&Wb[j & 1][(mt * 16 + l15) * XS + l16 * 8];
                acc[mt][0] = __builtin_amdgcn_mfma_f32_16x16x32_f16(wf, xf0, acc[mt][0], 0, 0, 0);
                acc[mt][1] = __builtin_amdgcn_mfma_f32_16x16x32_f16(wf, xf1, acc[mt][1], 0, 0, 0);
            }
        }
        if (j + 1 < 4) {
            stageX(j + 1, (j + 1) & 1, (j + 1) & 1); stageW((j + 1) & 1, (j + 1) & 1);
            asm volatile("s_waitcnt lgkmcnt(0)\n\ts_barrier" ::: "memory");
        }
    }

    // leaf layer 2 -> lout (local rows)
#pragma unroll
    for (int mt = 0; mt < 8; mt++)
#pragma unroll
        for (int nt = 0; nt < 2; nt++)
#pragma unroll
            for (int r = 0; r < 4; r++)
                acc[mt][nt][r] = fmaxf(acc[mt][nt][r], 0.01f * acc[mt][nt][r]);
#pragma unroll
    for (int nt = 0; nt < 2; ++nt) {
        h8 A[4];
#pragma unroll
        for (int kt = 0; kt < 4; kt++) {
            v4u av = {pkh(acc[2 * kt][nt][0], acc[2 * kt][nt][1]),
                      pkh(acc[2 * kt][nt][2], acc[2 * kt][nt][3]),
                      pkh(acc[2 * kt + 1][nt][0], acc[2 * kt + 1][nt][1]),
                      pkh(acc[2 * kt + 1][nt][2], acc[2 * kt + 1][nt][3])};
            A[kt] = __builtin_bit_cast(h8, av);
        }
        const int tb = wv * 32 + nt * 16;
#pragma unroll
        for (int qt = 0; qt < 3; ++qt) {
            f32x4 o = {0.f, 0.f, 0.f, 0.f};
#pragma unroll
            for (int kt = 0; kt < 4; kt++) {
                v4u wvv = ((const v4u*)w2f)[(kt * 3 + qt) * 64 + lane];
                o = __builtin_amdgcn_mfma_f32_16x16x32_f16(
                    A[kt], __builtin_bit_cast(h8, wvv), o, 0, 0, 0);
            }
            int q = qt * 16 + l15;
            if (q < OUT) {
#pragma unroll
                for (int r = 0; r < 4; r++) {
                    int row = tb + l16 * 4 + r;
                    float v = o[r] + b2v[qt];
                    v = fmaxf(v, 0.01f * v);
                    lout[row * XS + q] = f2h(v);
                }
            }
        }
    }

    // =============== PASS 2: d3 (NC=6, child from lout) ===============
#pragma unroll
    for (int mt = 0; mt < 8; mt++) { acc[mt][0] = bi0[mt]; acc[mt][1] = bi0[mt]; }

    issueX2(0, 0); issueW(0, 0);
    issueX2(1, 1); issueW(1, 1);
    stageX(0, 0, 0); stageW(0, 0);
    asm volatile("s_waitcnt lgkmcnt(0)\n\ts_barrier" ::: "memory");  // also fences lout

#pragma unroll
    for (int j = 0; j < 6; ++j) {
        if (j + 2 < 6) { issueX2(j + 2, j & 1); issueW(j + 2, j & 1); }
        {
            h8 xf[2];
#pragma unroll
            for (int nt = 0; nt < 2; ++nt) {
                int r = wv * 32 + nt * 16 + l15;
                if (j < 4) {
                    xf[nt] = *(const h8*)&Xb[j & 1][r * XS + l16 * 8];
                } else if (j == 4) {
                    xf[nt] = (l16 < 2) ? *(const h8*)&Xb[j & 1][r * XS + l16 * 8]
                                       : *(const h8*)&lout[r * XS + (l16 - 2) * 8];
                } else {
                    if (l16 < 3) xf[nt] = *(const h8*)&lout[r * XS + 16 + l16 * 8];
                    else { h8 z = {}; xf[nt] = z; }
                }
            }
#pragma unroll
            for (int mt = 0; mt < 8; ++mt) {
                h8 wf = *(const h8*)&Wb[j & 1][(mt * 16 + l15) * XS + l16 * 8];
                acc[mt][0] = __builtin_amdgcn_mfma_f32_16x16x32_f16(wf, xf[0], acc[mt][0], 0, 0, 0);
                acc[mt][1] = __builtin_amdgcn_mfma_f32_16x16x32_f16(wf, xf[1], acc[mt][1], 0, 0, 0);
            }
        }
        if (j + 1 < 6) {
            stageX(j + 1, (j + 1) & 1, (j + 1) & 1); stageW((j + 1) & 1, (j + 1) & 1);
            asm volatile("s_waitcnt lgkmcnt(0)\n\ts_barrier" ::: "memory");
        }
    }

    // d3 layer 2 -> sibling-summed global f16
#pragma unroll
    for (int mt = 0; mt < 8; mt++)
#pragma unroll
        for (int nt = 0; nt < 2; nt++)
#pragma unroll
            for (int r = 0; r < 4; r++)
                acc[mt][nt][r] = fmaxf(acc[mt][nt][r], 0.01f * acc[mt][nt][r]);
#pragma unroll
    for (int nt = 0; nt < 2; ++nt) {
        h8 A[4];
#pragma unroll
        for (int kt = 0; kt < 4; kt++) {
            v4u av = {pkh(acc[2 * kt][nt][0], acc[2 * kt][nt][1]),
                      pkh(acc[2 * kt][nt][2], acc[2 * kt][nt][3]),
                      pkh(acc[2 * kt + 1][nt][0], acc[2 * kt + 1][nt][1]),
                      pkh(acc[2 * kt + 1][nt][2], acc[2 * kt + 1][nt][3])};
            A[kt] = __builtin_bit_cast(h8, av);
        }
        const int tb = wv * 32 + nt * 16;
#pragma unroll
        for (int qt = 0; qt < 3; ++qt) {
            f32x4 o = {0.f, 0.f, 0.f, 0.f};
#pragma unroll
            for (int kt = 0; kt < 4; kt++) {
                v4u wvv = ((const v4u*)w2f)[(kt * 3 + qt) * 64 + lane];
                o = __builtin_amdgcn_mfma_f32_16x16x32_f16(
                    A[kt], __builtin_bit_cast(h8, wvv), o, 0, 0, 0);
            }
            int q = qt * 16 + l15;
            float s = 0.f;
#pragma unroll
            for (int r = 0; r < 4; r++) {
                float v = o[r] + b2v[qt];
                s += fmaxf(v, 0.01f * v);
            }
            if (q < OUT) {
                int p = (base >> 2) + (tb >> 2) + l16;
                outp[(size_t)p * 40 + q] = f2h(s);
            }
        }
    }
}

extern "C" void kernel_launch(void* const* d_in, const int* in_sizes, int n_in,
                              void* d_out, int out_size, void* d_ws, size_t ws_size,
                              hipStream_t stream) {
    const float* node_msg = (const float*)d_in[0];
    const float* bonds = (const float*)d_in[1];
    const float* W1 = (const float*)d_in[2];
    const float* b1 = (const float*)d_in[3];
    const float* W2 = (const float*)d_in[4];
    const float* b2 = (const float*)d_in[5];
    float* out = (float*)d_out;

    char* ws = (char*)d_ws;
    unsigned short* bufA = (unsigned short*)ws;                   // scratch (<=2.6 MB used)
    unsigned short* bufB = (unsigned short*)(ws + 41943040);      // d3 parents 10.5 MB
    unsigned short* w1f = (unsigned short*)(ws + 52428800);       // 49152 B
    unsigned int* w2f = (unsigned int*)(ws + 52428800 + 49152);   // 12288 B

    prep_w1<<<96, 256, 0, stream>>>(W1, w1f);
    prep_w2<<<1, 256, 0, stream>>>(W2, w2f);

    // fused leaf (d=4) + d=3: 524288 leaf rows, 524288 edges -> 131072 parents
    fused_ld3<<<4096, 256, 0, stream>>>(
        node_msg + (size_t)175104 * 125, node_msg + (size_t)43008 * 125,
        bonds + (size_t)172032 * 12, w1f, w2f, b1, b2, bufB);
    // d=2: 131072 edges -> 32768 parents -> bufA
    level_k<6, 1><<<1024, 256, 0, stream>>>(
        node_msg + (size_t)10240 * 125, bonds + (size_t)40960 * 12, bufB,
        w1f, w2f, b1, b2, bufA);
    // d=1: 32768 edges -> 8192 parents -> bufB (front, d2 already consumed)
    level_k<6, 1><<<256, 256, 0, stream>>>(
        node_msg + (size_t)2048 * 125, bonds + (size_t)8192 * 12, bufA,
        w1f, w2f, b1, b2, bufB);
    // d=0: 8192 edges -> 2048 parents -> out (fp32)
    level_k<6, 2><<<64, 256, 0, stream>>>(
        node_msg, bonds, bufB, w1f, w2f, b1, b2, out);
}

// Round 11
// 201.890 us; speedup vs baseline: 1.4357x; 1.4357x over previous
//
#include <hip/hip_runtime.h>
#include <hip/hip_bf16.h>
#include <cstddef>

// K=2048, B=4, D=5, ATOM=125, BOND=12, HID=125, OUT=40
// NOFF = [0, 2048, 10240, 43008, 175104, 699392]
// BOFF = [0, 8192, 40960, 172032, 696320]
//
// Round 11: barrier-free wave-autonomous level kernels.
//  - Each wave owns 32 consecutive rows; its inputs are CONTIGUOUS memory:
//    leaf msg 16000 B; mid msg 4000 B (8 parents), bonds 1536 B, child 2560 B.
//    Wave stages its region flat (raw f32 / raw f16) into a private LDS
//    segment via coalesced dwordx4 -- single-segment-per-instruction (fixes
//    the TA scatter bottleneck of r8-r10), no cross-wave sharing, NO barriers.
//  - X fragments: LDS b32 reads (conflict-free by 125/12-stride analysis) +
//    RNE cvt to f16.
//  - W1 packed per-fragment-contiguous in ws (w1g[((kc*8+mt)*64+ln)*8+j]):
//    one 1 KB coalesced dwordx4 per (chunk,mt) per wave, L1/L2-hot. No W LDS.
//  - W2 frag-packed as before (validated mapping), direct from cache.
//  - Leaf output bounced via LDS -> coalesced dwordx4 global stores.
//  - 5 split kernels (r9 structure; fusion regressed in r10).
// k' layout (192): [0,125) msg, [125,128) 0, [128,140) bond, [140,144) 0,
// [144,184) child, [184,192) 0. f16 everywhere, RNE. Intermediates [row][40] f16.

typedef __attribute__((ext_vector_type(8))) _Float16 h8;
typedef __attribute__((ext_vector_type(4))) float f32x4;
typedef __attribute__((ext_vector_type(4))) unsigned int v4u;

static constexpr int HID = 125, OUT = 40;

__device__ __forceinline__ unsigned short f2h(float x) {
    _Float16 h = (_Float16)x;  // RNE
    return __builtin_bit_cast(unsigned short, h);
}
__device__ __forceinline__ unsigned int pkh(float a, float b) {
    return (unsigned int)f2h(a) | ((unsigned int)f2h(b) << 16);
}

// W1 packed per-fragment: element (kc,mt,ln,j) -> hid = mt*16+(ln&15),
// k' = kc*32+(ln>>4)*8+j. 6*8*64*8 = 24576 f16 = 48 KB.
__global__ void prep_w1g(const float* __restrict__ W1, unsigned short* __restrict__ w1g) {
    int idx = blockIdx.x * 256 + threadIdx.x;
    if (idx >= 6 * 8 * 64 * 8) return;
    int j = idx & 7, ln = (idx >> 3) & 63, mt = (idx >> 9) & 7, kc = idx >> 12;
    int hid = mt * 16 + (ln & 15);
    int kp = kc * 32 + ((ln >> 4) << 3) + j;
    int k = (kp < 125) ? kp
          : (kp >= 128 && kp < 140) ? kp - 3
          : (kp >= 144 && kp < 184) ? kp - 7 : -1;
    float v = (k >= 0 && hid < HID) ? W1[(size_t)k * HID + hid] : 0.f;
    w1g[idx] = f2h(v);
}

// W2 frag-packed (validated): fr = kt*3+qt; elem j: hid = kt*32+16*(j>>2)+
// (ln>>4)*4+(j&3); q = qt*16+(ln&15).
__global__ void prep_w2(const float* __restrict__ W2, unsigned int* __restrict__ w2f) {
    int t = threadIdx.x;
    for (int task = t; task < 12 * 64; task += 256) {
        int ln = task & 63, fr = task >> 6;
        int kt = fr / 3, qt = fr % 3;
        int q = qt * 16 + (ln & 15);
        unsigned int w[4];
#pragma unroll
        for (int jp = 0; jp < 4; jp++) {
            unsigned short e[2];
#pragma unroll
            for (int s = 0; s < 2; s++) {
                int j = jp * 2 + s;
                int hid = kt * 32 + ((j >> 2) << 4) + ((ln >> 4) << 2) + (j & 3);
                float v = (hid < HID && q < OUT) ? W2[(size_t)hid * OUT + q] : 0.f;
                e[s] = f2h(v);
            }
            w[jp] = (unsigned int)e[0] | ((unsigned int)e[1] << 16);
        }
        v4u val = {w[0], w[1], w[2], w[3]};
        ((v4u*)w2f)[fr * 64 + ln] = val;
    }
}

// ========================= leaf kernel (d=4) =========================
__global__ void __launch_bounds__(256, 2)
leaf_k(const float* __restrict__ msg, const unsigned short* __restrict__ w1g,
       const unsigned int* __restrict__ w2f,
       const float* __restrict__ b1, const float* __restrict__ b2,
       unsigned short* __restrict__ outp) {
    __shared__ float Xs[4][4000];  // per-wave raw f32: 32 rows x 125

    const int tid = threadIdx.x;
    const int lane = tid & 63;
    const int wv = tid >> 6;
    const int l15 = tid & 15;
    const int l16 = (tid >> 4) & 3;
    const int row0 = blockIdx.x * 128 + wv * 32;

    // ---- stage: 16000 B contiguous, coalesced dwordx4, wave-private ----
    {
        const f32x4* src = (const f32x4*)(msg + (size_t)row0 * 125);
        f32x4* dst = (f32x4*)&Xs[wv][0];
#pragma unroll
        for (int i = 0; i < 16; i++) {
            int u = lane + i * 64;
            if (i < 15 || u < 1000) dst[u] = src[u];
        }
    }

    f32x4 acc[8][2];
#pragma unroll
    for (int mt = 0; mt < 8; mt++) {
        f32x4 bi;
#pragma unroll
        for (int r = 0; r < 4; r++) {
            int h_ = mt * 16 + l16 * 4 + r;
            bi[r] = (h_ < HID) ? b1[h_] : 0.f;
        }
        acc[mt][0] = bi;
        acc[mt][1] = bi;
    }

    // ---- layer 1: 4 chunks, fragments from LDS, W direct from cache ----
#pragma unroll
    for (int j = 0; j < 4; ++j) {
        h8 xf[2];
#pragma unroll
        for (int nt = 0; nt < 2; ++nt) {
            const float* rp = &Xs[wv][(nt * 16 + l15) * 125];
            const int k0 = j * 32 + l16 * 8;
            float t[8];
#pragma unroll
            for (int i = 0; i < 8; i++) {
                int col = k0 + i;
                int cs = (col < 125) ? col : 0;   // address clamp (stay in segment)
                float v = rp[cs];
                t[i] = (col < 125) ? v : 0.f;
            }
            v4u xv = {pkh(t[0], t[1]), pkh(t[2], t[3]), pkh(t[4], t[5]), pkh(t[6], t[7])};
            xf[nt] = __builtin_bit_cast(h8, xv);
        }
#pragma unroll
        for (int mt = 0; mt < 8; ++mt) {
            h8 wf = *(const h8*)&w1g[(size_t)((j * 8 + mt) * 64 + lane) * 8];
            acc[mt][0] = __builtin_amdgcn_mfma_f32_16x16x32_f16(wf, xf[0], acc[mt][0], 0, 0, 0);
            acc[mt][1] = __builtin_amdgcn_mfma_f32_16x16x32_f16(wf, xf[1], acc[mt][1], 0, 0, 0);
        }
    }

    // ---- lrelu + layer 2 (registers; validated construction) ----
#pragma unroll
    for (int mt = 0; mt < 8; mt++)
#pragma unroll
        for (int nt = 0; nt < 2; nt++)
#pragma unroll
            for (int r = 0; r < 4; r++)
                acc[mt][nt][r] = fmaxf(acc[mt][nt][r], 0.01f * acc[mt][nt][r]);

    float b2v[3];
#pragma unroll
    for (int qt = 0; qt < 3; qt++) {
        int q = qt * 16 + l15;
        b2v[qt] = (q < OUT) ? b2[q] : 0.f;
    }

    unsigned short* s16 = (unsigned short*)&Xs[wv][0];  // out-bounce (reads done)
#pragma unroll
    for (int nt = 0; nt < 2; ++nt) {
        h8 A[4];
#pragma unroll
        for (int kt = 0; kt < 4; kt++) {
            v4u av = {pkh(acc[2 * kt][nt][0], acc[2 * kt][nt][1]),
                      pkh(acc[2 * kt][nt][2], acc[2 * kt][nt][3]),
                      pkh(acc[2 * kt + 1][nt][0], acc[2 * kt + 1][nt][1]),
                      pkh(acc[2 * kt + 1][nt][2], acc[2 * kt + 1][nt][3])};
            A[kt] = __builtin_bit_cast(h8, av);
        }
#pragma unroll
        for (int qt = 0; qt < 3; ++qt) {
            f32x4 o = {0.f, 0.f, 0.f, 0.f};
#pragma unroll
            for (int kt = 0; kt < 4; kt++) {
                v4u wvv = ((const v4u*)w2f)[(kt * 3 + qt) * 64 + lane];
                o = __builtin_amdgcn_mfma_f32_16x16x32_f16(
                    A[kt], __builtin_bit_cast(h8, wvv), o, 0, 0, 0);
            }
            int q = qt * 16 + l15;
            if (q < OUT) {
#pragma unroll
                for (int r = 0; r < 4; r++) {
                    int rl = nt * 16 + l16 * 4 + r;  // local row in wave
                    float v = o[r] + b2v[qt];
                    v = fmaxf(v, 0.01f * v);
                    s16[rl * 40 + q] = f2h(v);
                }
            }
        }
    }
    // coalesced store: 32 rows x 40 f16 = 2560 B
    {
        v4u* gdst = (v4u*)(outp + (size_t)row0 * 40);
        const v4u* s4 = (const v4u*)s16;
#pragma unroll
        for (int i = 0; i < 3; i++) {
            int u = lane + i * 64;
            if (i < 2 || u < 160) gdst[u] = s4[u];
        }
    }
}

// ========================= mid/final kernel =========================
// MODE 1: sibling-summed f16 out; MODE 2: sibling-summed fp32 out (final).
template <int MODE>
__global__ void __launch_bounds__(256, 4)
mid_k(const float* __restrict__ msg, const float* __restrict__ bonds,
      const unsigned short* __restrict__ child,
      const unsigned short* __restrict__ w1g, const unsigned int* __restrict__ w2f,
      const float* __restrict__ b1, const float* __restrict__ b2,
      void* __restrict__ outp) {
    __shared__ float MS[4][1000];            // 8 parents x 125 f32
    __shared__ float BS[4][384];             // 32 rows x 12 f32
    __shared__ unsigned short CS[4][1280];   // 32 rows x 40 f16

    const int tid = threadIdx.x;
    const int lane = tid & 63;
    const int wv = tid >> 6;
    const int l15 = tid & 15;
    const int l16 = (tid >> 4) & 3;
    const int row0 = blockIdx.x * 128 + wv * 32;  // edge rows
    const int par0 = row0 >> 2;                   // parent rows

    // ---- stage (all wave-private, contiguous, coalesced) ----
    {
        const f32x4* sm = (const f32x4*)(msg + (size_t)par0 * 125);
        f32x4* dm = (f32x4*)&MS[wv][0];
#pragma unroll
        for (int i = 0; i < 4; i++) {
            int u = lane + i * 64;
            if (i < 3 || u < 250) dm[u] = sm[u];
        }
        const f32x4* sb = (const f32x4*)(bonds + (size_t)row0 * 12);
        f32x4* db = (f32x4*)&BS[wv][0];
#pragma unroll
        for (int i = 0; i < 2; i++) {
            int u = lane + i * 64;
            if (i < 1 || u < 96) db[u] = sb[u];
        }
        const v4u* sc = (const v4u*)(child + (size_t)row0 * 40);
        v4u* dc = (v4u*)&CS[wv][0];
#pragma unroll
        for (int i = 0; i < 3; i++) {
            int u = lane + i * 64;
            if (i < 2 || u < 160) dc[u] = sc[u];
        }
    }

    f32x4 acc[8][2];
#pragma unroll
    for (int mt = 0; mt < 8; mt++) {
        f32x4 bi;
#pragma unroll
        for (int r = 0; r < 4; r++) {
            int h_ = mt * 16 + l16 * 4 + r;
            bi[r] = (h_ < HID) ? b1[h_] : 0.f;
        }
        acc[mt][0] = bi;
        acc[mt][1] = bi;
    }

    // ---- layer 1: 6 chunks ----
#pragma unroll
    for (int j = 0; j < 6; ++j) {
        h8 xf[2];
#pragma unroll
        for (int nt = 0; nt < 2; ++nt) {
            const int rl = nt * 16 + l15;  // local edge row 0..31
            if (j < 4) {
                const float* pp = &MS[wv][(rl >> 2) * 125];
                const int k0 = j * 32 + l16 * 8;
                float t[8];
#pragma unroll
                for (int i = 0; i < 8; i++) {
                    int col = k0 + i;
                    int cs = (col < 125) ? col : 0;
                    float v = pp[cs];
                    t[i] = (col < 125) ? v : 0.f;
                }
                v4u xv = {pkh(t[0], t[1]), pkh(t[2], t[3]), pkh(t[4], t[5]), pkh(t[6], t[7])};
                xf[nt] = __builtin_bit_cast(h8, xv);
            } else if (j == 4) {
                if (l16 < 2) {
                    const float* bp = &BS[wv][rl * 12];
                    float t[8];
#pragma unroll
                    for (int i = 0; i < 8; i++) {
                        int c = l16 * 8 + i;
                        int cs = (c < 12) ? c : 0;
                        float v = bp[cs];
                        t[i] = (c < 12) ? v : 0.f;
                    }
                    v4u xv = {pkh(t[0], t[1]), pkh(t[2], t[3]), pkh(t[4], t[5]), pkh(t[6], t[7])};
                    xf[nt] = __builtin_bit_cast(h8, xv);
                } else {
                    xf[nt] = *(const h8*)&CS[wv][rl * 40 + (l16 - 2) * 8];  // child 0..15
                }
            } else {
                if (l16 < 3) {
                    xf[nt] = *(const h8*)&CS[wv][rl * 40 + 16 + l16 * 8];   // child 16..39
                } else {
                    h8 z = {};
                    xf[nt] = z;
                }
            }
        }
#pragma unroll
        for (int mt = 0; mt < 8; ++mt) {
            h8 wf = *(const h8*)&w1g[(size_t)((j * 8 + mt) * 64 + lane) * 8];
            acc[mt][0] = __builtin_amdgcn_mfma_f32_16x16x32_f16(wf, xf[0], acc[mt][0], 0, 0, 0);
            acc[mt][1] = __builtin_amdgcn_mfma_f32_16x16x32_f16(wf, xf[1], acc[mt][1], 0, 0, 0);
        }
    }

    // ---- lrelu + layer 2 + sibling sum ----
#pragma unroll
    for (int mt = 0; mt < 8; mt++)
#pragma unroll
        for (int nt = 0; nt < 2; nt++)
#pragma unroll
            for (int r = 0; r < 4; r++)
                acc[mt][nt][r] = fmaxf(acc[mt][nt][r], 0.01f * acc[mt][nt][r]);

    float b2v[3];
#pragma unroll
    for (int qt = 0; qt < 3; qt++) {
        int q = qt * 16 + l15;
        b2v[qt] = (q < OUT) ? b2[q] : 0.f;
    }
#pragma unroll
    for (int nt = 0; nt < 2; ++nt) {
        h8 A[4];
#pragma unroll
        for (int kt = 0; kt < 4; kt++) {
            v4u av = {pkh(acc[2 * kt][nt][0], acc[2 * kt][nt][1]),
                      pkh(acc[2 * kt][nt][2], acc[2 * kt][nt][3]),
                      pkh(acc[2 * kt + 1][nt][0], acc[2 * kt + 1][nt][1]),
                      pkh(acc[2 * kt + 1][nt][2], acc[2 * kt + 1][nt][3])};
            A[kt] = __builtin_bit_cast(h8, av);
        }
#pragma unroll
        for (int qt = 0; qt < 3; ++qt) {
            f32x4 o = {0.f, 0.f, 0.f, 0.f};
#pragma unroll
            for (int kt = 0; kt < 4; kt++) {
                v4u wvv = ((const v4u*)w2f)[(kt * 3 + qt) * 64 + lane];
                o = __builtin_amdgcn_mfma_f32_16x16x32_f16(
                    A[kt], __builtin_bit_cast(h8, wvv), o, 0, 0, 0);
            }
            int q = qt * 16 + l15;
            float s = 0.f;
#pragma unroll
            for (int r = 0; r < 4; r++) {
                float v = o[r] + b2v[qt];
                s += fmaxf(v, 0.01f * v);
            }
            if (q < OUT) {
                int p = par0 + nt * 4 + l16;
                if (MODE == 1)
                    ((unsigned short*)outp)[(size_t)p * 40 + q] = f2h(s);
                else
                    ((float*)outp)[(size_t)p * 40 + q] = s;
            }
        }
    }
}

extern "C" void kernel_launch(void* const* d_in, const int* in_sizes, int n_in,
                              void* d_out, int out_size, void* d_ws, size_t ws_size,
                              hipStream_t stream) {
    const float* node_msg = (const float*)d_in[0];
    const float* bonds = (const float*)d_in[1];
    const float* W1 = (const float*)d_in[2];
    const float* b1 = (const float*)d_in[3];
    const float* W2 = (const float*)d_in[4];
    const float* b2 = (const float*)d_in[5];
    float* out = (float*)d_out;

    char* ws = (char*)d_ws;
    unsigned short* bufA = (unsigned short*)ws;                   // 524288*40 f16
    unsigned short* bufB = (unsigned short*)(ws + 41943040);      // 131072*40 f16
    unsigned short* w1g = (unsigned short*)(ws + 52428800);       // 49152 B
    unsigned int* w2f = (unsigned int*)(ws + 52428800 + 49152);   // 12288 B

    prep_w1g<<<96, 256, 0, stream>>>(W1, w1g);
    prep_w2<<<1, 256, 0, stream>>>(W2, w2f);

    // leaf (d=4): 524288 rows -> bufA
    leaf_k<<<4096, 256, 0, stream>>>(
        node_msg + (size_t)175104 * 125, w1g, w2f, b1, b2, bufA);
    // d=3: 524288 edges -> 131072 parents -> bufB
    mid_k<1><<<4096, 256, 0, stream>>>(
        node_msg + (size_t)43008 * 125, bonds + (size_t)172032 * 12, bufA,
        w1g, w2f, b1, b2, bufB);
    // d=2: 131072 edges -> 32768 parents -> bufA
    mid_k<1><<<1024, 256, 0, stream>>>(
        node_msg + (size_t)10240 * 125, bonds + (size_t)40960 * 12, bufB,
        w1g, w2f, b1, b2, bufA);
    // d=1: 32768 edges -> 8192 parents -> bufB
    mid_k<1><<<256, 256, 0, stream>>>(
        node_msg + (size_t)2048 * 125, bonds + (size_t)8192 * 12, bufA,
        w1g, w2f, b1, b2, bufB);
    // d=0: 8192 edges -> 2048 parents -> out (fp32)
    mid_k<2><<<64, 256, 0, stream>>>(
        node_msg, bonds, bufB, w1g, w2f, b1, b2, out);
}